// Round 5
// baseline (212.243 us; speedup 1.0000x reference)
//
#include <hip/hip_runtime.h>
#include <math.h>

#define NN 8192
typedef unsigned int u32;

__device__ __forceinline__ int sdot4(u32 a, u32 b, int c) {
#if __has_builtin(__builtin_amdgcn_sdot4)
  return __builtin_amdgcn_sdot4((int)a, (int)b, c, false);
#else
  c += ((int)(a << 24) >> 24) * ((int)(b << 24) >> 24);
  c += ((int)(a << 16) >> 24) * ((int)(b << 16) >> 24);
  c += ((int)(a << 8) >> 24) * ((int)(b << 8) >> 24);
  c += (((int)a) >> 24) * (((int)b) >> 24);
  return c;
#endif
}

// ---------------------------------------------------------------------------
// Pass 1: h0 = adj_f32 @ [dfp,dts] (exact f32); emit adj8s = (round(adj*255)
// XOR 0x80) signed bytes + per-row byte-sums Rq; fused MLP_l0 -> cur0 +
// per-block feature-max partials.
// 512 blocks x 512 thr. Block owns 16 consecutive rows; per row the block
// reads quarters (8 KiB each) so the block sweeps a contiguous 512-KiB slab.
// Thread t owns k = q*2048 + 4t .. +3 (x0 fragment register-resident).
// ---------------------------------------------------------------------------
__global__ __launch_bounds__(512) void pass1_kernel(
    const float* __restrict__ adj, u32* __restrict__ adj8,
    u32* __restrict__ Rq,
    const float* __restrict__ dfp, const float* __restrict__ dts,
    const float* __restrict__ W1, const float* __restrict__ b1,
    const float* __restrict__ W2, const float* __restrict__ b2,
    float* __restrict__ cur, float* __restrict__ partial) {
  const int tid = threadIdx.x;
  const int wave = tid >> 6, lane = tid & 63;
  const int rbase = blockIdx.x * 16;
  __shared__ float redF[8][8];
  __shared__ u32 redU[8][4];
  __shared__ float finF[8];
  __shared__ float wmax[4][8];

  // x0 fragments for this thread's 4 quarter-positions (register-resident)
  float pv[4][4], sv[4][4];
#pragma unroll
  for (int q = 0; q < 4; ++q) {
    float4 t1 = *(const float4*)(dfp + q * 2048 + 4 * tid);
    float4 t2 = *(const float4*)(dts + q * 2048 + 4 * tid);
    pv[q][0] = t1.x; pv[q][1] = t1.y; pv[q][2] = t1.z; pv[q][3] = t1.w;
    sv[q][0] = t2.x; sv[q][1] = t2.y; sv[q][2] = t2.z; sv[q][3] = t2.w;
  }
  float mxv = 0.f;

  for (int g = 0; g < 4; ++g) {
    float accP[4] = {0.f, 0.f, 0.f, 0.f};
    float accS[4] = {0.f, 0.f, 0.f, 0.f};
    u32 accR[4] = {0, 0, 0, 0};
    float4 A[4], B[4];
#pragma unroll
    for (int r = 0; r < 4; ++r)
      A[r] = *(const float4*)(adj + (size_t)(rbase + g * 4 + r) * NN + 4 * tid);
#pragma unroll
    for (int q = 0; q < 4; ++q) {
      if (q < 3) {
#pragma unroll
        for (int r = 0; r < 4; ++r)
          B[r] = *(const float4*)(adj + (size_t)(rbase + g * 4 + r) * NN +
                                  (q + 1) * 2048 + 4 * tid);
      }
#pragma unroll
      for (int r = 0; r < 4; ++r) {
        const float a0 = A[r].x, a1 = A[r].y, a2 = A[r].z, a3 = A[r].w;
        accP[r] = fmaf(a0, pv[q][0], accP[r]);
        accP[r] = fmaf(a1, pv[q][1], accP[r]);
        accP[r] = fmaf(a2, pv[q][2], accP[r]);
        accP[r] = fmaf(a3, pv[q][3], accP[r]);
        accS[r] = fmaf(a0, sv[q][0], accS[r]);
        accS[r] = fmaf(a1, sv[q][1], accS[r]);
        accS[r] = fmaf(a2, sv[q][2], accS[r]);
        accS[r] = fmaf(a3, sv[q][3], accS[r]);
        u32 q0 = (u32)fmaf(a0, 255.f, 0.5f);
        u32 q1 = (u32)fmaf(a1, 255.f, 0.5f);
        u32 q2 = (u32)fmaf(a2, 255.f, 0.5f);
        u32 q3 = (u32)fmaf(a3, 255.f, 0.5f);
        accR[r] += q0 + q1 + q2 + q3;
        adj8[(size_t)(rbase + g * 4 + r) * 2048 + q * 512 + tid] =
            (q0 | (q1 << 8) | (q2 << 16) | (q3 << 24)) ^ 0x80808080u;
      }
      if (q < 3) {
#pragma unroll
        for (int r = 0; r < 4; ++r) A[r] = B[r];
      }
    }
    // block-wide reduce of hp, hs (f32) and Rq (exact u32) for 4 rows
#pragma unroll
    for (int r = 0; r < 4; ++r) {
      for (int off = 32; off; off >>= 1) {
        accP[r] += __shfl_xor(accP[r], off, 64);
        accS[r] += __shfl_xor(accS[r], off, 64);
        accR[r] += (u32)__shfl_xor((int)accR[r], off, 64);
      }
    }
    if (lane == 0) {
#pragma unroll
      for (int r = 0; r < 4; ++r) {
        redF[wave][r] = accP[r];
        redF[wave][4 + r] = accS[r];
        redU[wave][r] = accR[r];
      }
    }
    __syncthreads();
    if (tid < 8) {
      float s = 0.f;
      for (int w = 0; w < 8; ++w) s += redF[w][tid];
      finF[tid] = s;
    } else if (tid < 12) {
      u32 s = 0;
      for (int w = 0; w < 8; ++w) s += redU[w][tid - 8];
      Rq[rbase + g * 4 + (tid - 8)] = s;
    }
    __syncthreads();
    // fused MLP_l0: wave r handles row g*4+r, lane j<8 owns feature j
    if (wave < 4) {
      const int row = rbase + g * 4 + wave;
      const float hp = finF[wave], hs = finF[4 + wave];
      const int j = lane & 7;
      float z = fmaf(hp, W1[j], fmaf(hs, W1[8 + j], b1[j]));
      z = fmaxf(z, 0.f);
      float o = b2[j];
#pragma unroll
      for (int jj = 0; jj < 8; ++jj)
        o = fmaf(__shfl(z, jj, 64), W2[jj * 8 + j], o);
      float val = fmaxf(o, 0.f);
      if (lane < 8) {
        cur[(size_t)row * 8 + j] = val;
        mxv = fmaxf(mxv, val);
      }
    }
  }
  if (wave < 4 && lane < 8) wmax[wave][lane] = mxv;
  __syncthreads();
  if (tid < 8)
    partial[blockIdx.x * 8 + tid] = fmaxf(fmaxf(wmax[0][tid], wmax[1][tid]),
                                          fmaxf(wmax[2][tid], wmax[3][tid]));
}

// ---------------------------------------------------------------------------
// Passes 2/3: h = (adj8/255) @ x via signed sdot4 + exact integer offset
// correction: sum(a_q*x_q) = dot_s + 128*Rq_row + 128*Cq_j - 128^2*N.
// 512 blocks x 512 thr, 16 rows/block. Thread t owns k = 16t..16t+15 with
// x quantized into 32 registers ONCE (no LDS in main loop). Per row the
// block reads the whole 8-KiB adj8 row coalesced (sequential slab sweep).
// HEADS=0: fused MLP_l1 -> cur1 + partials.  HEADS=1: pol/val heads.
// ---------------------------------------------------------------------------
template <int HEADS>
__global__ __launch_bounds__(512) void pass23_kernel(
    const u32* __restrict__ adj8, const float* __restrict__ x,
    const u32* __restrict__ Rq, const float* __restrict__ partial,
    const float* __restrict__ W1, const float* __restrict__ b1,
    const float* __restrict__ W2, const float* __restrict__ b2,
    const float* __restrict__ W1v, const float* __restrict__ b1v,
    const float* __restrict__ W2v, const float* __restrict__ b2v,
    float* __restrict__ out0, float* __restrict__ out1,
    float* __restrict__ partial_out) {
  const int tid = threadIdx.x;
  const int wave = tid >> 6, lane = tid & 63;
  const int rbase = blockIdx.x * 16;
  __shared__ float sqs[8], sds[8];
  __shared__ float redM[8][8];
  __shared__ u32 redC[8][8];
  __shared__ int sCq[8];
  __shared__ int redD[8][32];
  __shared__ int finD[32];
  __shared__ float wmax[4][8];

  // issue adj8 prefetches for rows 0,1 early (overlap with staging)
  uint4 A = *(const uint4*)(adj8 + (size_t)rbase * 2048 + 4 * tid);
  uint4 Bn = *(const uint4*)(adj8 + (size_t)(rbase + 1) * 2048 + 4 * tid);

  // --- per-feature max from producer partials (512 rows) -> scales ---
  float pm[8];
  {
    float4 a = *(const float4*)(partial + tid * 8);
    float4 b = *(const float4*)(partial + tid * 8 + 4);
    pm[0] = a.x; pm[1] = a.y; pm[2] = a.z; pm[3] = a.w;
    pm[4] = b.x; pm[5] = b.y; pm[6] = b.z; pm[7] = b.w;
  }
  for (int off = 32; off; off >>= 1)
#pragma unroll
    for (int j = 0; j < 8; ++j) pm[j] = fmaxf(pm[j], __shfl_xor(pm[j], off, 64));
  if (lane == 0)
#pragma unroll
    for (int j = 0; j < 8; ++j) redM[wave][j] = pm[j];
  __syncthreads();
  if (tid < 8) {
    float m2 = 0.f;
#pragma unroll
    for (int w = 0; w < 8; ++w) m2 = fmaxf(m2, redM[w][tid]);
    m2 = fmaxf(m2, 1e-20f);
    sqs[tid] = 255.f / m2;
    sds[tid] = m2 / 65025.f;
  }
  __syncthreads();

  // --- quantize this thread's 16 x-rows into registers (signed bytes) ---
  float qs[8];
#pragma unroll
  for (int j = 0; j < 8; ++j) qs[j] = sqs[j];
  u32 xq[8][4];
#pragma unroll
  for (int j = 0; j < 8; ++j)
#pragma unroll
    for (int d = 0; d < 4; ++d) xq[j][d] = 0;
  u32 cs[8] = {0, 0, 0, 0, 0, 0, 0, 0};
#pragma unroll
  for (int kk = 0; kk < 16; ++kk) {
    const float* xp = x + ((size_t)tid * 16 + kk) * 8;
    float4 a = *(const float4*)xp;
    float4 b = *(const float4*)(xp + 4);
    const float e[8] = {a.x, a.y, a.z, a.w, b.x, b.y, b.z, b.w};
#pragma unroll
    for (int j = 0; j < 8; ++j) {
      u32 qv = (u32)fmaf(e[j], qs[j], 0.5f);
      cs[j] += qv;
      xq[j][kk >> 2] |= (qv ^ 0x80u) << (8 * (kk & 3));
    }
  }
  // Cq block reduce (exact integers)
  for (int off = 32; off; off >>= 1)
#pragma unroll
    for (int j = 0; j < 8; ++j) cs[j] += (u32)__shfl_xor((int)cs[j], off, 64);
  if (lane == 0)
#pragma unroll
    for (int j = 0; j < 8; ++j) redC[wave][j] = cs[j];
  __syncthreads();
  if (tid < 8) {
    u32 s = 0;
#pragma unroll
    for (int w = 0; w < 8; ++w) s += redC[w][tid];
    sCq[tid] = (int)s;
  }
  __syncthreads();

  // --- main loop: 16 rows, whole-row coalesced reads, pure sdot4 ---
  for (int g = 0; g < 4; ++g) {
    int accD[4][8];
#pragma unroll
    for (int r = 0; r < 4; ++r)
#pragma unroll
      for (int j = 0; j < 8; ++j) accD[r][j] = 0;
#pragma unroll
    for (int r = 0; r < 4; ++r) {
      const int nrr = (g * 4 + r + 2) & 15;  // rows 16,17 wrap: harmless
      uint4 C = *(const uint4*)(adj8 + (size_t)(rbase + nrr) * 2048 + 4 * tid);
#pragma unroll
      for (int j = 0; j < 8; ++j) {
        int c = accD[r][j];
        c = sdot4(A.x, xq[j][0], c);
        c = sdot4(A.y, xq[j][1], c);
        c = sdot4(A.z, xq[j][2], c);
        c = sdot4(A.w, xq[j][3], c);
        accD[r][j] = c;
      }
      A = Bn;
      Bn = C;
    }
    // block reduce 32 exact ints
#pragma unroll
    for (int r = 0; r < 4; ++r)
#pragma unroll
      for (int j = 0; j < 8; ++j)
        for (int off = 32; off; off >>= 1)
          accD[r][j] += __shfl_xor(accD[r][j], off, 64);
    if (lane == 0)
#pragma unroll
      for (int r = 0; r < 4; ++r)
#pragma unroll
        for (int j = 0; j < 8; ++j) redD[wave][r * 8 + j] = accD[r][j];
    __syncthreads();
    if (tid < 32) {
      int s = 0;
#pragma unroll
      for (int w = 0; w < 8; ++w) s += redD[w][tid];
      finD[tid] = s;
    }
    __syncthreads();
    if (HEADS == 0) {
      if (wave < 4) {
        const int row = rbase + g * 4 + wave;
        const int j = lane & 7;
        int hi = finD[wave * 8 + j] + 128 * (int)Rq[row] + 128 * sCq[j] -
                 134217728;  // 128*128*8192
        float h = (float)hi * sds[j];
        float z = b1[j];
#pragma unroll
        for (int d = 0; d < 8; ++d)
          z = fmaf(__shfl(h, d, 64), W1[d * 8 + j], z);
        z = fmaxf(z, 0.f);
        float o = b2[j];
#pragma unroll
        for (int jj = 0; jj < 8; ++jj)
          o = fmaf(__shfl(z, jj, 64), W2[jj * 8 + j], o);
        float val = fmaxf(o, 0.f);
        if (lane < 8) {
          out0[(size_t)row * 8 + j] = val;
          if (wave == (g & 3) || true) wmaxv_dummy:;
        }
      }
    } else {
      if (wave < 4 && lane == 0) {
        const int row = rbase + g * 4 + wave;
        const int rq = 128 * (int)Rq[row];
        float zp = b1[0], zv = b1v[0];
#pragma unroll
        for (int d = 0; d < 8; ++d) {
          int hi = finD[wave * 8 + d] + rq + 128 * sCq[d] - 134217728;
          float h = (float)hi * sds[d];
          zp = fmaf(h, W1[d], zp);
          zv = fmaf(h, W1v[d], zv);
        }
        zp = fmaxf(zp, 0.f);
        zv = fmaxf(zv, 0.f);
        out0[row] = fmaf(zp, W2[0], b2[0]);
        out1[row] = fmaf(zv, W2v[0], b2v[0]);
      }
    }
  }
  if (HEADS == 0) {
    // feature-max partial: recompute from out0 writes tracked per thread is
    // complex across groups; instead waves 0-3 lanes 0-7 re-read their rows.
    float mxv = 0.f;
    if (wave < 4 && lane < 8) {
#pragma unroll
      for (int g = 0; g < 4; ++g)
        mxv = fmaxf(mxv, out0[(size_t)(rbase + g * 4 + wave) * 8 + lane]);
      wmax[wave][lane] = mxv;
    }
    __syncthreads();
    if (tid < 8)
      partial_out[blockIdx.x * 8 + tid] =
          fmaxf(fmaxf(wmax[0][tid], wmax[1][tid]),
                fmaxf(wmax[2][tid], wmax[3][tid]));
  }
}

// ---------------------------------------------------------------------------
// Fused reductions + finalize (single 1024-thr block; data stays in regs).
// ---------------------------------------------------------------------------
__global__ __launch_bounds__(1024) void reduce_finalize_kernel(
    float* __restrict__ out) {
  const int tid = threadIdx.x, wave = tid >> 6, lane = tid & 63;
  __shared__ float sa[16], sb[16], sc[4];

  float4 l0 = *(const float4*)(out + tid * 8);
  float4 l1 = *(const float4*)(out + tid * 8 + 4);
  float4 v0 = *(const float4*)(out + NN + tid * 8);
  float4 v1 = *(const float4*)(out + NN + tid * 8 + 4);
  const float lv[8] = {l0.x, l0.y, l0.z, l0.w, l1.x, l1.y, l1.z, l1.w};
  const float vv[8] = {v0.x, v0.y, v0.z, v0.w, v1.x, v1.y, v1.z, v1.w};

  float m = -3.4e38f, s = 0.f;
#pragma unroll
  for (int i = 0; i < 8; ++i) {
    m = fmaxf(m, lv[i]);
    s += vv[i];
  }
  for (int off = 32; off; off >>= 1) {
    m = fmaxf(m, __shfl_xor(m, off, 64));
    s += __shfl_xor(s, off, 64);
  }
  if (lane == 0) { sa[wave] = m; sb[wave] = s; }
  __syncthreads();
  if (tid == 0) {
    float mm = sa[0], ss = sb[0];
    for (int i = 1; i < 16; ++i) { mm = fmaxf(mm, sa[i]); ss += sb[i]; }
    sc[0] = mm; sc[1] = ss * (1.f / NN);
  }
  __syncthreads();
  m = sc[0];
  const float mean = sc[1];

  float el[8];
  float e = 0.f, v2 = 0.f;
#pragma unroll
  for (int i = 0; i < 8; ++i) {
    el[i] = expf(lv[i] - m);
    e += el[i];
    float d = vv[i] - mean;
    v2 = fmaf(d, d, v2);
  }
  for (int off = 32; off; off >>= 1) {
    e += __shfl_xor(e, off, 64);
    v2 += __shfl_xor(v2, off, 64);
  }
  if (lane == 0) { sa[wave] = e; sb[wave] = v2; }
  __syncthreads();
  if (tid == 0) {
    float ee = sa[0], vvv = sb[0];
    for (int i = 1; i < 16; ++i) { ee += sa[i]; vvv += sb[i]; }
    sc[2] = 1.f / ee;
    sc[3] = 1.f / sqrtf(vvv * (1.f / NN) + 1e-10f);
  }
  __syncthreads();
  const float inv_e = sc[2], inv_std = sc[3];
  float4 o0, o1, w0, w1;
  o0.x = el[0] * inv_e; o0.y = el[1] * inv_e;
  o0.z = el[2] * inv_e; o0.w = el[3] * inv_e;
  o1.x = el[4] * inv_e; o1.y = el[5] * inv_e;
  o1.z = el[6] * inv_e; o1.w = el[7] * inv_e;
  w0.x = (vv[0] - mean) * inv_std; w0.y = (vv[1] - mean) * inv_std;
  w0.z = (vv[2] - mean) * inv_std; w0.w = (vv[3] - mean) * inv_std;
  w1.x = (vv[4] - mean) * inv_std; w1.y = (vv[5] - mean) * inv_std;
  w1.z = (vv[6] - mean) * inv_std; w1.w = (vv[7] - mean) * inv_std;
  *(float4*)(out + tid * 8) = o0;
  *(float4*)(out + tid * 8 + 4) = o1;
  *(float4*)(out + NN + tid * 8) = w0;
  *(float4*)(out + NN + tid * 8 + 4) = w1;
}

// ---------------------------------------------------------------------------
extern "C" void kernel_launch(void* const* d_in, const int* in_sizes, int n_in,
                              void* d_out, int out_size, void* d_ws,
                              size_t ws_size, hipStream_t stream) {
  const float* adj = (const float*)d_in[0];
  const float* dfp = (const float*)d_in[1];
  const float* dts = (const float*)d_in[2];
  const float* W1_l0 = (const float*)d_in[3];
  const float* b1_l0 = (const float*)d_in[4];
  const float* W2_l0 = (const float*)d_in[5];
  const float* b2_l0 = (const float*)d_in[6];
  const float* W1_l1 = (const float*)d_in[7];
  const float* b1_l1 = (const float*)d_in[8];
  const float* W2_l1 = (const float*)d_in[9];
  const float* b2_l1 = (const float*)d_in[10];
  const float* W1_pol = (const float*)d_in[11];
  const float* b1_pol = (const float*)d_in[12];
  const float* W2_pol = (const float*)d_in[13];
  const float* b2_pol = (const float*)d_in[14];
  const float* W1_val = (const float*)d_in[15];
  const float* b1_val = (const float*)d_in[16];
  const float* W2_val = (const float*)d_in[17];
  const float* b2_val = (const float*)d_in[18];

  char* base = (char*)d_ws;
  u32* adj8 = (u32*)base;                                  // 64 MiB
  u32* Rq = (u32*)(base + (size_t)NN * NN);                // 32 KiB
  float* curA = (float*)(base + (size_t)NN * NN + NN * 4); // [N][8]
  float* curB = curA + NN * 8;
  float* partialA = curB + NN * 8;       // [512][8]
  float* partialB = partialA + 512 * 8;  // [512][8]
  float* logits = (float*)d_out;
  float* value = logits + NN;

  pass1_kernel<<<512, 512, 0, stream>>>(adj, adj8, Rq, dfp, dts, W1_l0, b1_l0,
                                        W2_l0, b2_l0, curA, partialA);
  pass23_kernel<0><<<512, 512, 0, stream>>>(
      adj8, curA, Rq, partialA, W1_l1, b1_l1, W2_l1, b2_l1, W1_l1, b1_l1,
      W2_l1, b2_l1, curB, curB, partialB);
  pass23_kernel<1><<<512, 512, 0, stream>>>(
      adj8, curB, Rq, partialB, W1_pol, b1_pol, W2_pol, b2_pol, W1_val, b1_val,
      W2_val, b2_val, logits, value, partialB);
  reduce_finalize_kernel<<<1, 1024, 0, stream>>>((float*)d_out);
}

// Round 6
// 137.778 us; speedup vs baseline: 1.5405x; 1.5405x over previous
//
#include <hip/hip_runtime.h>
#include <math.h>

#define NN 8192
typedef unsigned int u32;
typedef unsigned char u8;

__device__ __forceinline__ u32 dot4u(u32 a, u32 b, u32 c) {
#if __has_builtin(__builtin_amdgcn_udot4)
  return __builtin_amdgcn_udot4(a, b, c, false);
#else
  c += (a & 0xffu) * (b & 0xffu);
  c += ((a >> 8) & 0xffu) * ((b >> 8) & 0xffu);
  c += ((a >> 16) & 0xffu) * ((b >> 16) & 0xffu);
  c += (a >> 24) * (b >> 24);
  return c;
#endif
}

// ---------------------------------------------------------------------------
// Pass 1: h0 = adj_f32 @ [dfp,dts] (exact f32); emit adj8 = round(adj*255)
// unsigned bytes; fused MLP_l0 -> cur0 + per-block feature-max partials.
// 1024 blocks x 256 thr (4 waves). Wave owns 2 rows across FULL k (single
// butterfly at end, no cross-wave reduction). Chunk = 512 floats; lane reads
// float4 at 4*lane + 256*i (unit-stride 1-KiB wave reads); prefetch chunk+1
// (4 KiB/wave in flight, 16 waves/CU).
// ---------------------------------------------------------------------------
__global__ __launch_bounds__(256) void pass1_kernel(
    const float* __restrict__ adj, u32* __restrict__ adj8,
    const float* __restrict__ dfp, const float* __restrict__ dts,
    const float* __restrict__ W1, const float* __restrict__ b1,
    const float* __restrict__ W2, const float* __restrict__ b2,
    float* __restrict__ cur, float* __restrict__ partial) {
  const int tid = threadIdx.x, wave = tid >> 6, lane = tid & 63;
  const int row0 = blockIdx.x * 8 + wave * 2;
  __shared__ float wmax[4][8];

  const float* rowp0 = adj + (size_t)row0 * NN;
  const float* rowp1 = adj + (size_t)(row0 + 1) * NN;
  u32* qp0 = adj8 + (size_t)row0 * (NN / 4);
  u32* qp1 = adj8 + (size_t)(row0 + 1) * (NN / 4);

  float acc0[2] = {0.f, 0.f}, acc1[2] = {0.f, 0.f};
  float4 A[2][2], B[2][2];
#pragma unroll
  for (int i = 0; i < 2; ++i) {
    A[0][i] = *(const float4*)(rowp0 + 256 * i + 4 * lane);
    A[1][i] = *(const float4*)(rowp1 + 256 * i + 4 * lane);
  }
  for (int c = 0; c < 16; ++c) {
    const int kb = 512 * c;
    if (c < 15) {
#pragma unroll
      for (int i = 0; i < 2; ++i) {
        B[0][i] = *(const float4*)(rowp0 + kb + 512 + 256 * i + 4 * lane);
        B[1][i] = *(const float4*)(rowp1 + kb + 512 + 256 * i + 4 * lane);
      }
    }
    float4 xp[2], xs[2];
#pragma unroll
    for (int i = 0; i < 2; ++i) {
      xp[i] = *(const float4*)(dfp + kb + 256 * i + 4 * lane);
      xs[i] = *(const float4*)(dts + kb + 256 * i + 4 * lane);
    }
#pragma unroll
    for (int r = 0; r < 2; ++r) {
#pragma unroll
      for (int i = 0; i < 2; ++i) {
        const float4 a4 = A[r][i];
        acc0[r] = fmaf(a4.x, xp[i].x, acc0[r]);
        acc0[r] = fmaf(a4.y, xp[i].y, acc0[r]);
        acc0[r] = fmaf(a4.z, xp[i].z, acc0[r]);
        acc0[r] = fmaf(a4.w, xp[i].w, acc0[r]);
        acc1[r] = fmaf(a4.x, xs[i].x, acc1[r]);
        acc1[r] = fmaf(a4.y, xs[i].y, acc1[r]);
        acc1[r] = fmaf(a4.z, xs[i].z, acc1[r]);
        acc1[r] = fmaf(a4.w, xs[i].w, acc1[r]);
        u32 q0 = (u32)fmaf(a4.x, 255.f, 0.5f);
        u32 q1 = (u32)fmaf(a4.y, 255.f, 0.5f);
        u32 q2 = (u32)fmaf(a4.z, 255.f, 0.5f);
        u32 q3 = (u32)fmaf(a4.w, 255.f, 0.5f);
        (r ? qp1 : qp0)[128 * c + 64 * i + lane] =
            q0 | (q1 << 8) | (q2 << 16) | (q3 << 24);
      }
    }
#pragma unroll
    for (int r = 0; r < 2; ++r) {
      A[r][0] = B[r][0];
      A[r][1] = B[r][1];
    }
  }
  // single full-wave butterfly: every lane gets complete row sums
#pragma unroll
  for (int r = 0; r < 2; ++r) {
    for (int off = 32; off; off >>= 1) {
      acc0[r] += __shfl_xor(acc0[r], off, 64);
      acc1[r] += __shfl_xor(acc1[r], off, 64);
    }
  }
  const int j = lane & 7;
  float mxv = 0.f;
#pragma unroll
  for (int r = 0; r < 2; ++r) {
    float z = fmaf(acc0[r], W1[j], fmaf(acc1[r], W1[8 + j], b1[j]));
    z = fmaxf(z, 0.f);
    float o = b2[j];
#pragma unroll
    for (int jj = 0; jj < 8; ++jj)
      o = fmaf(__shfl(z, jj, 64), W2[jj * 8 + j], o);
    float val = fmaxf(o, 0.f);
    if (lane < 8) cur[(size_t)(row0 + r) * 8 + j] = val;
    mxv = fmaxf(mxv, val);
  }
  if (lane < 8) wmax[wave][lane] = mxv;
  __syncthreads();
  if (tid < 8)
    partial[blockIdx.x * 8 + tid] = fmaxf(fmaxf(wmax[0][tid], wmax[1][tid]),
                                          fmaxf(wmax[2][tid], wmax[3][tid]));
}

// ---------------------------------------------------------------------------
// Passes 2/3: h = (adj8/255) @ x via unsigned udot4 (exact i32 accumulation).
// x quantized per-feature to u8, staged DIRECTLY feature-major in 64-KiB LDS
// (2 blocks/CU). 512 blocks x 512 thr; wave owns 2 rows across full k
// (single butterfly at end). Chunk = 1024 bytes (uint4/lane), prefetch
// depth 2.  HEADS=0: fused MLP_l1 + partials.  HEADS=1: pol/val heads.
// ---------------------------------------------------------------------------
template <int HEADS>
__global__ __launch_bounds__(512) void pass23_kernel(
    const u32* __restrict__ adj8, const float* __restrict__ x,
    const float* __restrict__ partial, int nprod,
    const float* __restrict__ W1, const float* __restrict__ b1,
    const float* __restrict__ W2, const float* __restrict__ b2,
    const float* __restrict__ W1v, const float* __restrict__ b1v,
    const float* __restrict__ W2v, const float* __restrict__ b2v,
    float* __restrict__ out0, float* __restrict__ out1,
    float* __restrict__ partial_out) {
  __shared__ u32 sxT[8 * 2048];  // 64 KiB, feature-major: dword p = rows 4p..4p+3
  __shared__ float redM[8][8];
  __shared__ float sqs[8], sds[8];
  __shared__ float wmax[8][8];
  const int tid = threadIdx.x, wave = tid >> 6, lane = tid & 63;
  const int row0 = blockIdx.x * 16 + wave * 2;

  const u32* r0p = adj8 + (size_t)row0 * 2048;
  const u32* r1p = adj8 + (size_t)(row0 + 1) * 2048;
  // issue first two adj chunks early (overlap with scales + staging)
  uint4 A[2], Bp[2];
  A[0] = *(const uint4*)(r0p + 4 * lane);
  A[1] = *(const uint4*)(r1p + 4 * lane);
  Bp[0] = *(const uint4*)(r0p + 256 + 4 * lane);
  Bp[1] = *(const uint4*)(r1p + 256 + 4 * lane);

  // --- per-feature max from producer partials -> quant/dequant scales ---
  float pm[8] = {0.f, 0.f, 0.f, 0.f, 0.f, 0.f, 0.f, 0.f};
  for (int p = tid; p < nprod; p += 512) {
    float4 a = *(const float4*)(partial + p * 8);
    float4 b = *(const float4*)(partial + p * 8 + 4);
    pm[0] = fmaxf(pm[0], a.x); pm[1] = fmaxf(pm[1], a.y);
    pm[2] = fmaxf(pm[2], a.z); pm[3] = fmaxf(pm[3], a.w);
    pm[4] = fmaxf(pm[4], b.x); pm[5] = fmaxf(pm[5], b.y);
    pm[6] = fmaxf(pm[6], b.z); pm[7] = fmaxf(pm[7], b.w);
  }
  for (int off = 32; off; off >>= 1)
#pragma unroll
    for (int j = 0; j < 8; ++j) pm[j] = fmaxf(pm[j], __shfl_xor(pm[j], off, 64));
  if (lane == 0)
#pragma unroll
    for (int j = 0; j < 8; ++j) redM[wave][j] = pm[j];
  __syncthreads();
  if (tid < 8) {
    float m2 = 0.f;
#pragma unroll
    for (int w = 0; w < 8; ++w) m2 = fmaxf(m2, redM[w][tid]);
    m2 = fmaxf(m2, 1e-20f);
    sqs[tid] = 255.f / m2;
    sds[tid] = m2 / 65025.f;
  }
  __syncthreads();

  // --- stage x directly feature-major: thread packs 4 consecutive rows/dword
  float qs[8];
#pragma unroll
  for (int j = 0; j < 8; ++j) qs[j] = sqs[j];
  for (int gi = 0; gi < 4; ++gi) {
    const int p = gi * 512 + tid;  // dword index; rows 4p..4p+3
    u32 pk[8] = {0, 0, 0, 0, 0, 0, 0, 0};
#pragma unroll
    for (int m = 0; m < 4; ++m) {
      const float* xr = x + (size_t)(4 * p + m) * 8;
      float4 a = *(const float4*)xr;
      float4 b = *(const float4*)(xr + 4);
      const float e[8] = {a.x, a.y, a.z, a.w, b.x, b.y, b.z, b.w};
#pragma unroll
      for (int j = 0; j < 8; ++j)
        pk[j] |= ((u32)fmaf(e[j], qs[j], 0.5f)) << (8 * m);
    }
#pragma unroll
    for (int j = 0; j < 8; ++j) sxT[j * 2048 + p] = pk[j];  // conflict-free
  }
  __syncthreads();

  // --- main loop: 8 chunks of 1024 k, pure udot4, depth-2 prefetch ---
  u32 acc[2][8] = {};
  for (int c = 0; c < 8; ++c) {
    uint4 C[2];
    if (c + 2 < 8) {
      C[0] = *(const uint4*)(r0p + 256 * (c + 2) + 4 * lane);
      C[1] = *(const uint4*)(r1p + 256 * (c + 2) + 4 * lane);
    } else {
      C[0] = A[0];
      C[1] = A[1];
    }
    uint4 xq[8];
#pragma unroll
    for (int jj = 0; jj < 8; ++jj)
      xq[jj] = ((const uint4*)sxT)[jj * 512 + 64 * c + lane];
#pragma unroll
    for (int r = 0; r < 2; ++r) {
      const uint4 a4 = A[r];
#pragma unroll
      for (int jj = 0; jj < 8; ++jj) {
        u32 cc = acc[r][jj];
        cc = dot4u(a4.x, xq[jj].x, cc);
        cc = dot4u(a4.y, xq[jj].y, cc);
        cc = dot4u(a4.z, xq[jj].z, cc);
        cc = dot4u(a4.w, xq[jj].w, cc);
        acc[r][jj] = cc;
      }
    }
    A[0] = Bp[0]; A[1] = Bp[1];
    Bp[0] = C[0]; Bp[1] = C[1];
  }
  // single butterfly -> full sums in all lanes; dequantize
#pragma unroll
  for (int r = 0; r < 2; ++r)
#pragma unroll
    for (int jj = 0; jj < 8; ++jj)
      for (int off = 32; off; off >>= 1)
        acc[r][jj] += (u32)__shfl_xor((int)acc[r][jj], off, 64);
  float h[2][8];
#pragma unroll
  for (int r = 0; r < 2; ++r)
#pragma unroll
    for (int jj = 0; jj < 8; ++jj) h[r][jj] = (float)acc[r][jj] * sds[jj];

  if (HEADS == 0) {
    const int j = lane & 7;
    float mxv = 0.f;
#pragma unroll
    for (int r = 0; r < 2; ++r) {
      float z = b1[j];
#pragma unroll
      for (int d = 0; d < 8; ++d) z = fmaf(h[r][d], W1[d * 8 + j], z);
      z = fmaxf(z, 0.f);
      float o = b2[j];
#pragma unroll
      for (int jj = 0; jj < 8; ++jj)
        o = fmaf(__shfl(z, jj, 64), W2[jj * 8 + j], o);
      float val = fmaxf(o, 0.f);
      if (lane < 8) out0[(size_t)(row0 + r) * 8 + j] = val;
      mxv = fmaxf(mxv, val);
    }
    if (lane < 8) wmax[wave][lane] = mxv;
    __syncthreads();
    if (tid < 8) {
      float m2 = 0.f;
#pragma unroll
      for (int w = 0; w < 8; ++w) m2 = fmaxf(m2, wmax[w][tid]);
      partial_out[blockIdx.x * 8 + tid] = m2;
    }
  } else {
    if (lane == 0) {
#pragma unroll
      for (int r = 0; r < 2; ++r) {
        float zp = b1[0], zv = b1v[0];
#pragma unroll
        for (int d = 0; d < 8; ++d) {
          zp = fmaf(h[r][d], W1[d], zp);
          zv = fmaf(h[r][d], W1v[d], zv);
        }
        zp = fmaxf(zp, 0.f);
        zv = fmaxf(zv, 0.f);
        out0[row0 + r] = fmaf(zp, W2[0], b2[0]);
        out1[row0 + r] = fmaf(zv, W2v[0], b2v[0]);
      }
    }
  }
}

// ---------------------------------------------------------------------------
// Fused reductions + finalize (single 1024-thr block; data stays in regs).
// ---------------------------------------------------------------------------
__global__ __launch_bounds__(1024) void reduce_finalize_kernel(
    float* __restrict__ out) {
  const int tid = threadIdx.x, wave = tid >> 6, lane = tid & 63;
  __shared__ float sa[16], sb[16], sc[4];

  float4 l0 = *(const float4*)(out + tid * 8);
  float4 l1 = *(const float4*)(out + tid * 8 + 4);
  float4 v0 = *(const float4*)(out + NN + tid * 8);
  float4 v1 = *(const float4*)(out + NN + tid * 8 + 4);
  const float lv[8] = {l0.x, l0.y, l0.z, l0.w, l1.x, l1.y, l1.z, l1.w};
  const float vv[8] = {v0.x, v0.y, v0.z, v0.w, v1.x, v1.y, v1.z, v1.w};

  float m = -3.4e38f, s = 0.f;
#pragma unroll
  for (int i = 0; i < 8; ++i) {
    m = fmaxf(m, lv[i]);
    s += vv[i];
  }
  for (int off = 32; off; off >>= 1) {
    m = fmaxf(m, __shfl_xor(m, off, 64));
    s += __shfl_xor(s, off, 64);
  }
  if (lane == 0) { sa[wave] = m; sb[wave] = s; }
  __syncthreads();
  if (tid == 0) {
    float mm = sa[0], ss = sb[0];
    for (int i = 1; i < 16; ++i) { mm = fmaxf(mm, sa[i]); ss += sb[i]; }
    sc[0] = mm; sc[1] = ss * (1.f / NN);
  }
  __syncthreads();
  m = sc[0];
  const float mean = sc[1];

  float el[8];
  float e = 0.f, v2 = 0.f;
#pragma unroll
  for (int i = 0; i < 8; ++i) {
    el[i] = expf(lv[i] - m);
    e += el[i];
    float d = vv[i] - mean;
    v2 = fmaf(d, d, v2);
  }
  for (int off = 32; off; off >>= 1) {
    e += __shfl_xor(e, off, 64);
    v2 += __shfl_xor(v2, off, 64);
  }
  if (lane == 0) { sa[wave] = e; sb[wave] = v2; }
  __syncthreads();
  if (tid == 0) {
    float ee = sa[0], vvv = sb[0];
    for (int i = 1; i < 16; ++i) { ee += sa[i]; vvv += sb[i]; }
    sc[2] = 1.f / ee;
    sc[3] = 1.f / sqrtf(vvv * (1.f / NN) + 1e-10f);
  }
  __syncthreads();
  const float inv_e = sc[2], inv_std = sc[3];
  float4 o0, o1, w0, w1;
  o0.x = el[0] * inv_e; o0.y = el[1] * inv_e;
  o0.z = el[2] * inv_e; o0.w = el[3] * inv_e;
  o1.x = el[4] * inv_e; o1.y = el[5] * inv_e;
  o1.z = el[6] * inv_e; o1.w = el[7] * inv_e;
  w0.x = (vv[0] - mean) * inv_std; w0.y = (vv[1] - mean) * inv_std;
  w0.z = (vv[2] - mean) * inv_std; w0.w = (vv[3] - mean) * inv_std;
  w1.x = (vv[4] - mean) * inv_std; w1.y = (vv[5] - mean) * inv_std;
  w1.z = (vv[6] - mean) * inv_std; w1.w = (vv[7] - mean) * inv_std;
  *(float4*)(out + tid * 8) = o0;
  *(float4*)(out + tid * 8 + 4) = o1;
  *(float4*)(out + NN + tid * 8) = w0;
  *(float4*)(out + NN + tid * 8 + 4) = w1;
}

// ---------------------------------------------------------------------------
extern "C" void kernel_launch(void* const* d_in, const int* in_sizes, int n_in,
                              void* d_out, int out_size, void* d_ws,
                              size_t ws_size, hipStream_t stream) {
  const float* adj = (const float*)d_in[0];
  const float* dfp = (const float*)d_in[1];
  const float* dts = (const float*)d_in[2];
  const float* W1_l0 = (const float*)d_in[3];
  const float* b1_l0 = (const float*)d_in[4];
  const float* W2_l0 = (const float*)d_in[5];
  const float* b2_l0 = (const float*)d_in[6];
  const float* W1_l1 = (const float*)d_in[7];
  const float* b1_l1 = (const float*)d_in[8];
  const float* W2_l1 = (const float*)d_in[9];
  const float* b2_l1 = (const float*)d_in[10];
  const float* W1_pol = (const float*)d_in[11];
  const float* b1_pol = (const float*)d_in[12];
  const float* W2_pol = (const float*)d_in[13];
  const float* b2_pol = (const float*)d_in[14];
  const float* W1_val = (const float*)d_in[15];
  const float* b1_val = (const float*)d_in[16];
  const float* W2_val = (const float*)d_in[17];
  const float* b2_val = (const float*)d_in[18];

  char* base = (char*)d_ws;
  u32* adj8 = (u32*)base;                                   // 64 MiB
  float* curA = (float*)(base + (size_t)NN * NN);           // [N][8]
  float* curB = curA + NN * 8;                              // [N][8]
  float* partialA = curB + NN * 8;                          // [1024][8]
  float* partialB = partialA + 1024 * 8;                    // [512][8]
  float* logits = (float*)d_out;
  float* value = logits + NN;

  pass1_kernel<<<1024, 256, 0, stream>>>(adj, adj8, dfp, dts, W1_l0, b1_l0,
                                         W2_l0, b2_l0, curA, partialA);
  pass23_kernel<0><<<512, 512, 0, stream>>>(
      adj8, curA, partialA, 1024, W1_l1, b1_l1, W2_l1, b2_l1, W1_l1, b1_l1,
      W2_l1, b2_l1, curB, curB, partialB);
  pass23_kernel<1><<<512, 512, 0, stream>>>(
      adj8, curB, partialB, 512, W1_pol, b1_pol, W2_pol, b2_pol, W1_val,
      b1_val, W2_val, b2_val, logits, value, partialB);
  reduce_finalize_kernel<<<1, 1024, 0, stream>>>((float*)d_out);
}